// Round 22
// baseline (1171.913 us; speedup 1.0000x reference)
//
#include <hip/hip_runtime.h>

// VanillaRNN: BATCH=1024, SEQ=512, HID=512, OUT=10
// h <- tanh(W_hh @ h + W_hx x_t + b_h), 512 steps, then y = W_yh h + b_y.
//
// Round 26: champion (R23/R25, 1126us wall / 1103us dispatch) + the last
// untested mechanism: WXBH LDS STAGING. After barrier-1 both phase-locked
// waves enter the epilogue together; its 8 Whx/bh global loads (L1-hot,
// ~200cyc) are issued post-barrier with the VALU idle -> exposed latency
// every step. Registers can't hold them (R3/R6/R21: any +16 regs spills),
// but LDS can: pack {Whx,bh} as f16 pairs (2KB, 147456+2048<160K) in the
// prologue (1 coalesced dword/thread x2 -- no R24-style register peak),
// and the epilogue does 1 ds_read_b128 per mt (~120cyc, DS pipe idle in
// the epilogue anyway) instead of 2 global f32x4 loads. f16 Whx/bh
// precision proven in R7 (passed, same absmax). Main loop untouched.
// Gates: WRITE_SIZE 40KB (spill), VGPR<=128, absmax pass; flat -> revert
// R25 and close.
//
// ws: [1MB,1.5MB) W A-frags.

#define BATCH 1024
#define SEQT  512
#define HID   512
#define OUTD  10
#define KR    12   // kk-blocks (of K=32) in registers: K=384
#define NKK   16

typedef _Float16 f16;
typedef _Float16 f16x8 __attribute__((ext_vector_type(8)));
typedef _Float16 f16x4 __attribute__((ext_vector_type(4)));
typedef float    f32x4 __attribute__((ext_vector_type(4)));

// W_hh fp32 [H][H] -> fp16 A-fragment layout:
// entry ((g*4+mt)*16+kk)*64+lane = f16x8 of A[m][k],
// m = g*64+mt*16+(lane&15), k = kk*32+((lane>>4)&3)*8+j.
__global__ void wconv_kernel(const float* __restrict__ Whh, f16* __restrict__ frag) {
    int id = blockIdx.x * blockDim.x + threadIdx.x;   // 0..32767
    int lane = id & 63;
    int kk   = (id >> 6) & 15;
    int mt   = (id >> 10) & 3;
    int g    = id >> 12;
    int m = g * 64 + mt * 16 + (lane & 15);
    int k = kk * 32 + ((lane >> 4) & 3) * 8;
    const float* src = Whh + (size_t)m * HID + k;
    f16x8 v;
#pragma unroll
    for (int j = 0; j < 8; ++j) v[j] = (f16)src[j];
    *(f16x8*)(frag + (size_t)id * 8) = v;
}

__device__ __forceinline__ float fast_tanh(float v) {
    v = fminf(fmaxf(v, -15.f), 15.f);
    float e = __expf(2.f * v);
    return (e - 1.f) * __builtin_amdgcn_rcpf(e + 1.f);
}

__global__ __launch_bounds__(512)
__attribute__((amdgpu_waves_per_eu(2, 2)))
void rnn_cu(
    const f16* __restrict__ frag,   // W_hh A-frags (all 16 kk-blocks)
    const float* __restrict__ x,    // [B][T]
    const float* __restrict__ Whx,  // [H]
    const float* __restrict__ bh,   // [H]
    const float* __restrict__ Wyh,  // [OUT][H]
    const float* __restrict__ by,   // [OUT]
    float* __restrict__ out)        // [B][OUT]
{
    // HB first: its ds offsets (<16 KB) fit the 16-bit imm with lane-only base.
    __shared__ f16 HB[8192];                    // h, B-frag layout, 16 KB
    __shared__ f16 WXBH[1024];                  // {Whx,bh} f16 pairs, 2 KB
    __shared__ f16 WL[65536];                   // W A-frags kk 12..15, 128 KB

    const int tid  = threadIdx.x;
    const int w    = tid >> 6;       // wave = row-group of 64 rows
    const int lane = tid & 63;
    const int n    = lane & 15;      // batch col within group
    const int q    = lane >> 4;
    const int bg   = blockIdx.x;     // batch group: cols [bg*16, +16)

    // ---- h(0) = 0 ----
    {
        f16x8 z;
#pragma unroll
        for (int j = 0; j < 8; ++j) z[j] = (f16)0.f;
        *(f16x8*)&HB[tid * 16]     = z;
        *(f16x8*)&HB[tid * 16 + 8] = z;
    }

    // ---- stage {Whx,bh} as interleaved f16 pairs (1 dword/thread x2;
    //      no register peak -- R24's lesson) ----
    WXBH[2 * tid]     = (f16)Whx[tid];
    WXBH[2 * tid + 1] = (f16)bh[tid];

    const f16x8* A = (const f16x8*)frag;

    // ---- LDS W portion: wave w stages its (mt, kk 12..15) frags ----
#pragma unroll
    for (int mt = 0; mt < 4; ++mt)
#pragma unroll
        for (int kkl = 0; kkl < 4; ++kkl) {
            int e = ((w * 4 + mt) * 4 + kkl) * 64 + lane;
            *(f16x8*)&WL[e * 8] = A[((w * 4 + mt) * 16 + (KR + kkl)) * 64 + lane];
        }

    // ---- register W portion: kk 0..11, kk-major, static indices ----
    f16x8 Wr[KR * 4];
#pragma unroll
    for (int kk = 0; kk < KR; ++kk)
#pragma unroll
        for (int mt = 0; mt < 4; ++mt)
            Wr[kk * 4 + mt] = A[((w * 4 + mt) * 16 + kk) * 64 + lane];

    __syncthreads();

    const int b = bg * 16 + n;
    const float* xp = x + (size_t)b * SEQT;

#pragma unroll 1
    for (int s = 0; s < SEQT; ++s) {
        float xv = xp[s];

        f32x4 acc[4] = {{0,0,0,0},{0,0,0,0},{0,0,0,0},{0,0,0,0}};

        // ---- interleaved schedule: one LDS-W block per 4-slot chunk ----
        // t%4==0 -> tail block kk=12+(t>>2) (W from WL: 4 reads + 1 h read)
        // else   -> reg block rb=t-1-(t>>2)  (W from Wr: 1 h read)
#pragma unroll
        for (int t = 0; t < NKK; ++t) {
            constexpr int ord[NKK] = {12, 0, 1, 2, 13, 3, 4, 5,
                                      14, 6, 7, 8, 15, 9, 10, 11};
            const int kb = ord[t];
            f16x8 bf = *(const f16x8*)&HB[(kb * 64 + lane) * 8];
            if ((t & 3) == 0) {
                const int kkl = t >> 2;
#pragma unroll
                for (int mt = 0; mt < 4; ++mt) {
                    f16x8 a = *(const f16x8*)&WL[(((w * 4 + mt) * 4 + kkl) * 64 + lane) * 8];
                    acc[mt] = __builtin_amdgcn_mfma_f32_16x16x32_f16(
                        a, bf, acc[mt], 0, 0, 0);
                }
            } else {
                const int rb = t - 1 - (t >> 2);
#pragma unroll
                for (int mt = 0; mt < 4; ++mt)
                    acc[mt] = __builtin_amdgcn_mfma_f32_16x16x32_f16(
                        Wr[rb * 4 + mt], bf, acc[mt], 0, 0, 0);
            }
        }

        __syncthreads();   // all reads of h(s) done before in-place overwrite

        // Opaque WXBH base: its reads are loop-invariant; hoisting them
        // costs 16 regs -> spill (R21's failure mode).
        const f16* wxp = &WXBH[0];
        asm volatile("" : "+v"(wxp));

        // ---- epilogue: wxbh from LDS (~120cyc, DS idle here), tanh,
        //      write h(s+1) in B-frag layout (branch-free) ----
        // C layout: col n = lane&15, row m = w*64 + mt*16 + q*4 + r.
#pragma unroll
        for (int mt = 0; mt < 4; ++mt) {
            int m0 = w * 64 + mt * 16 + q * 4;
            f16x8 wb = *(const f16x8*)&wxp[2 * m0];   // {whx,bh} x4 pairs
            f16x4 hv;
#pragma unroll
            for (int r = 0; r < 4; ++r) {
                float pre = fmaf((float)wb[2 * r], xv, acc[mt][r])
                          + (float)wb[2 * r + 1];
                hv[r] = (f16)fast_tanh(pre);
            }
            int kkd = w * 2 + (mt >> 1);
            int q2  = (mt & 1) * 2 + (q >> 1);
            int j0  = (q & 1) * 4;
            *(f16x4*)&HB[(kkd * 64 + q2 * 16 + n) * 8 + j0] = hv;
        }

        __syncthreads();   // h(s+1) complete before next step's reads
    }

    // ---- fused y: out[b][o] = by[o] + sum_m Wyh[o][m] * h[m][b].
    // h(SEQT) for this WG's 16 cols is fully resident in HB:
    // 160 threads: nn = tid&15, o = tid>>4. Wyh rows are 2KB, L2-hot.
    if (tid < 16 * OUTD) {
        const int nn = tid & 15;
        const int o  = tid >> 4;
        const float* wrow = Wyh + (size_t)o * HID;
        float sum = by[o];
        for (int kk = 0; kk < 16; ++kk)
#pragma unroll
            for (int q2 = 0; q2 < 4; ++q2) {
                f16x8 hv = *(const f16x8*)&HB[((kk * 64 + q2 * 16 + nn)) * 8];
                const float* wp = wrow + kk * 32 + q2 * 8;
#pragma unroll
                for (int j = 0; j < 8; ++j) sum += wp[j] * (float)hv[j];
            }
        out[(size_t)(bg * 16 + nn) * OUTD + o] = sum;
    }
}

extern "C" void kernel_launch(void* const* d_in, const int* in_sizes, int n_in,
                              void* d_out, int out_size, void* d_ws, size_t ws_size,
                              hipStream_t stream) {
    const float* x   = (const float*)d_in[0];
    const float* Whx = (const float*)d_in[1];
    const float* Whh = (const float*)d_in[2];
    const float* Wyh = (const float*)d_in[3];
    const float* bh  = (const float*)d_in[4];
    const float* by  = (const float*)d_in[5];
    float* out = (float*)d_out;

    char* ws   = (char*)d_ws;
    f16*  frag = (f16*)(ws + (1 << 20));         // 512 KB @ 1MB

    wconv_kernel<<<128, 256, 0, stream>>>(Whh, frag);
    rnn_cu<<<64, 512, 0, stream>>>(frag, x, Whx, bh, Wyh, by, out);
}

// Round 23
// 1127.141 us; speedup vs baseline: 1.0397x; 1.0397x over previous
//
#include <hip/hip_runtime.h>

// VanillaRNN: BATCH=1024, SEQ=512, HID=512, OUT=10
// h <- tanh(W_hh @ h + W_hx x_t + b_h), 512 steps, then y = W_yh h + b_y.
//
// FINAL (Round 27) = the champion (R23/R25, twice-reproduced: 1126us wall,
// ~1103us dispatch; session start was 1307us).
// R26 falsified the last open mechanism (wxbh LDS staging, +45us): the
// epilogue's global loads sit on vmcnt (independent of DS traffic) and
// overlap the ds_write stream; moving them to LDS put them on lgkmcnt,
// serializing against the epilogue's own stores. Counter-pressure matters
// as much as pipe-pressure.
// Surviving wins: R13 pipe-duty interleave (+5%); R23 branch-free epilogue
// + LDS-resident y-fusion (+8%).
// Falsified with counters: W-from-global (R5), cross-CU M-split (R9),
// 1-wave ILP (R10), dataflow flags (R11), LDS-funded read-ahead (R12/R14),
// AGPR pinning (R15/R16: inline-asm MFMA bypasses the hazard recognizer),
// wave desync (R19), cross-barrier W-prefetch (R21), barrier removal +
// wconv fusion (R24), wxbh LDS staging (R26).
// Structural floor: W-residency (512KB/CU) == regfile budget -> zero
// registers for latency-hiding state -> ds_read latency exposed behind
// 2-wave TLP; both per-step barriers are load-bearing (phase-lock).
//
// ws: [1MB,1.5MB) W A-frags.

#define BATCH 1024
#define SEQT  512
#define HID   512
#define OUTD  10
#define KR    12   // kk-blocks (of K=32) in registers: K=384
#define NKK   16

typedef _Float16 f16;
typedef _Float16 f16x8 __attribute__((ext_vector_type(8)));
typedef _Float16 f16x4 __attribute__((ext_vector_type(4)));
typedef float    f32x4 __attribute__((ext_vector_type(4)));

// W_hh fp32 [H][H] -> fp16 A-fragment layout:
// entry ((g*4+mt)*16+kk)*64+lane = f16x8 of A[m][k],
// m = g*64+mt*16+(lane&15), k = kk*32+((lane>>4)&3)*8+j.
__global__ void wconv_kernel(const float* __restrict__ Whh, f16* __restrict__ frag) {
    int id = blockIdx.x * blockDim.x + threadIdx.x;   // 0..32767
    int lane = id & 63;
    int kk   = (id >> 6) & 15;
    int mt   = (id >> 10) & 3;
    int g    = id >> 12;
    int m = g * 64 + mt * 16 + (lane & 15);
    int k = kk * 32 + ((lane >> 4) & 3) * 8;
    const float* src = Whh + (size_t)m * HID + k;
    f16x8 v;
#pragma unroll
    for (int j = 0; j < 8; ++j) v[j] = (f16)src[j];
    *(f16x8*)(frag + (size_t)id * 8) = v;
}

__device__ __forceinline__ float fast_tanh(float v) {
    v = fminf(fmaxf(v, -15.f), 15.f);
    float e = __expf(2.f * v);
    return (e - 1.f) * __builtin_amdgcn_rcpf(e + 1.f);
}

__global__ __launch_bounds__(512)
__attribute__((amdgpu_waves_per_eu(2, 2)))
void rnn_cu(
    const f16* __restrict__ frag,   // W_hh A-frags (all 16 kk-blocks)
    const float* __restrict__ x,    // [B][T]
    const float* __restrict__ Whx,  // [H]
    const float* __restrict__ bh,   // [H]
    const float* __restrict__ Wyh,  // [OUT][H]
    const float* __restrict__ by,   // [OUT]
    float* __restrict__ out)        // [B][OUT]
{
    // HB first: its ds offsets (<16 KB) fit the 16-bit imm with lane-only base.
    __shared__ f16 HB[8192];                    // h, B-frag layout, 16 KB
    __shared__ f16 WL[65536];                   // W A-frags kk 12..15, 128 KB

    const int tid  = threadIdx.x;
    const int w    = tid >> 6;       // wave = row-group of 64 rows
    const int lane = tid & 63;
    const int n    = lane & 15;      // batch col within group
    const int q    = lane >> 4;
    const int bg   = blockIdx.x;     // batch group: cols [bg*16, +16)

    // ---- h(0) = 0 ----
    {
        f16x8 z;
#pragma unroll
        for (int j = 0; j < 8; ++j) z[j] = (f16)0.f;
        *(f16x8*)&HB[tid * 16]     = z;
        *(f16x8*)&HB[tid * 16 + 8] = z;
    }

    const f16x8* A = (const f16x8*)frag;

    // ---- LDS W portion: wave w stages its (mt, kk 12..15) frags ----
#pragma unroll
    for (int mt = 0; mt < 4; ++mt)
#pragma unroll
        for (int kkl = 0; kkl < 4; ++kkl) {
            int e = ((w * 4 + mt) * 4 + kkl) * 64 + lane;
            *(f16x8*)&WL[e * 8] = A[((w * 4 + mt) * 16 + (KR + kkl)) * 64 + lane];
        }

    // ---- register W portion: kk 0..11, kk-major, static indices ----
    f16x8 Wr[KR * 4];
#pragma unroll
    for (int kk = 0; kk < KR; ++kk)
#pragma unroll
        for (int mt = 0; mt < 4; ++mt)
            Wr[kk * 4 + mt] = A[((w * 4 + mt) * 16 + kk) * 64 + lane];

    __syncthreads();

    const int b = bg * 16 + n;
    const float* xp = x + (size_t)b * SEQT;

#pragma unroll 1
    for (int s = 0; s < SEQT; ++s) {
        float xv = xp[s];

        f32x4 acc[4] = {{0,0,0,0},{0,0,0,0},{0,0,0,0},{0,0,0,0}};

        // ---- interleaved schedule: one LDS-W block per 4-slot chunk ----
        // t%4==0 -> tail block kk=12+(t>>2) (W from WL: 4 reads + 1 h read)
        // else   -> reg block rb=t-1-(t>>2)  (W from Wr: 1 h read)
#pragma unroll
        for (int t = 0; t < NKK; ++t) {
            constexpr int ord[NKK] = {12, 0, 1, 2, 13, 3, 4, 5,
                                      14, 6, 7, 8, 15, 9, 10, 11};
            const int kb = ord[t];
            f16x8 bf = *(const f16x8*)&HB[(kb * 64 + lane) * 8];
            if ((t & 3) == 0) {
                const int kkl = t >> 2;
#pragma unroll
                for (int mt = 0; mt < 4; ++mt) {
                    f16x8 a = *(const f16x8*)&WL[(((w * 4 + mt) * 4 + kkl) * 64 + lane) * 8];
                    acc[mt] = __builtin_amdgcn_mfma_f32_16x16x32_f16(
                        a, bf, acc[mt], 0, 0, 0);
                }
            } else {
                const int rb = t - 1 - (t >> 2);
#pragma unroll
                for (int mt = 0; mt < 4; ++mt)
                    acc[mt] = __builtin_amdgcn_mfma_f32_16x16x32_f16(
                        Wr[rb * 4 + mt], bf, acc[mt], 0, 0, 0);
            }
        }

        __syncthreads();   // all reads of h(s) done before in-place overwrite

        // Block loop-invariant hoisting of Whx/bh (would cost 32 VGPRs and
        // push past the 256 budget -> spill). These loads sit on vmcnt and
        // overlap the epilogue's ds_write stream (R26: LDS-staging them
        // onto lgkmcnt serializes and costs +45us).
        const float* wbp = Whx;
        const float* bbp = bh;
        asm volatile("" : "+v"(wbp), "+v"(bbp));

        // ---- epilogue: tanh, write h(s+1) in B-frag layout (branch-free;
        //      the final h stays in LDS for the fused y phase) ----
        // C layout: col n = lane&15, row m = w*64 + mt*16 + q*4 + r.
#pragma unroll
        for (int mt = 0; mt < 4; ++mt) {
            int m0 = w * 64 + mt * 16 + q * 4;
            f32x4 whx4 = *(const f32x4*)(wbp + m0);
            f32x4 bh4  = *(const f32x4*)(bbp + m0);
            f16x4 hv;
#pragma unroll
            for (int r = 0; r < 4; ++r) {
                float pre = acc[mt][r] + whx4[r] * xv + bh4[r];
                hv[r] = (f16)fast_tanh(pre);
            }
            int kkd = w * 2 + (mt >> 1);
            int q2  = (mt & 1) * 2 + (q >> 1);
            int j0  = (q & 1) * 4;
            *(f16x4*)&HB[(kkd * 64 + q2 * 16 + n) * 8 + j0] = hv;
        }

        __syncthreads();   // h(s+1) complete before next step's reads
    }

    // ---- fused y: out[b][o] = by[o] + sum_m Wyh[o][m] * h[m][b].
    // h(SEQT) for this WG's 16 cols is fully resident in HB:
    // 160 threads: nn = tid&15, o = tid>>4. Wyh rows are 2KB, L2-hot.
    if (tid < 16 * OUTD) {
        const int nn = tid & 15;
        const int o  = tid >> 4;
        const float* wrow = Wyh + (size_t)o * HID;
        float sum = by[o];
        for (int kk = 0; kk < 16; ++kk)
#pragma unroll
            for (int q2 = 0; q2 < 4; ++q2) {
                f16x8 hv = *(const f16x8*)&HB[((kk * 64 + q2 * 16 + nn)) * 8];
                const float* wp = wrow + kk * 32 + q2 * 8;
#pragma unroll
                for (int j = 0; j < 8; ++j) sum += wp[j] * (float)hv[j];
            }
        out[(size_t)(bg * 16 + nn) * OUTD + o] = sum;
    }
}

extern "C" void kernel_launch(void* const* d_in, const int* in_sizes, int n_in,
                              void* d_out, int out_size, void* d_ws, size_t ws_size,
                              hipStream_t stream) {
    const float* x   = (const float*)d_in[0];
    const float* Whx = (const float*)d_in[1];
    const float* Whh = (const float*)d_in[2];
    const float* Wyh = (const float*)d_in[3];
    const float* bh  = (const float*)d_in[4];
    const float* by  = (const float*)d_in[5];
    float* out = (float*)d_out;

    char* ws   = (char*)d_ws;
    f16*  frag = (f16*)(ws + (1 << 20));         // 512 KB @ 1MB

    wconv_kernel<<<128, 256, 0, stream>>>(Whh, frag);
    rnn_cu<<<64, 512, 0, stream>>>(frag, x, Whx, bh, Wyh, by, out);
}